// Round 4
// baseline (395.855 us; speedup 1.0000x reference)
//
#include <hip/hip_runtime.h>
#include <math.h>

// Fused two-head classifier via bf16 MFMA GEMM:
//   C[65536 x 48] = embs[65536 x 1024] (bf16) x B[1024 x 48]
//   B cols 0..4 = W_status, 5..34 = W_flight, 35..47 = zero pad.
//
// Round-4: A staged through double-buffered LDS tiles (2 x 32 KB) with
// perfectly coalesced global loads (8 full 128B lines per wave-instr) and a
// one-barrier-per-k-step pipeline: compute tile k from LDS while tile k+1
// (loaded a full iteration earlier) is written and tile k+2 is issued.
// Issue-to-use distance ~= one HBM-paced iteration (~3200 cy) >> 900 cy
// latency, so the per-iter vmcnt wait never stalls. B in 48 KB LDS halves,
// fragment order, zero scalar loads in the hot loop.

typedef __bf16 bf16x8 __attribute__((ext_vector_type(8)));
typedef float  f32x4  __attribute__((ext_vector_type(4)));

#define KSTEPS  32
#define HALF_KS 16

__global__ __launch_bounds__(1024, 4)
void fused_heads_kernel(const float* __restrict__ embs,
                        const float* __restrict__ W_status,
                        const float* __restrict__ b_status,
                        const float* __restrict__ W_flight,
                        const float* __restrict__ b_flight,
                        float* __restrict__ out) {
    // A tiles: 2 x [256 rows][8 f4] fp32, col XOR-swizzled  -> 64 KB
    // B half:  [16 ks][3 frag][64 lanes] bf16x8             -> 48 KB
    __shared__ float4 Atile[2][256 * 8];
    __shared__ bf16x8 Bsh[HALF_KS * 3 * 64];

    const int tid  = threadIdx.x;
    const int lane = tid & 63;
    const int wv   = tid >> 6;          // 0..15
    const int n    = lane & 15;         // MFMA row (A) / col (C)
    const int q    = lane >> 4;         // quad group 0..3
    const int row0 = blockIdx.x * 256;

    const float4* E4 = (const float4*)embs;       // [65536][256]

    // staging map: thread handles rows (tid>>3) and (tid>>3)+128, f4 col tid&7
    const int srow = tid >> 3;          // 0..127
    const int sc4  = tid & 7;           // 0..7
    const int sswz = sc4 ^ (srow & 7);  // (srow+128)&7 == srow&7

    // compute map
    const int abase = (wv * 16 + n) * 8;
    const int aswz  = n & 7;

    // ---- B staging (per half), same verified mapping as round 3 ----
    auto stageB = [&](int half) {
#pragma unroll
        for (int i = 0; i < 3; ++i) {
            const int d   = tid + i * 1024;
            const int L   = d & 63;
            const int ksf = d >> 6;                    // ksl*3 + f
            const int ksl = ksf / 3;
            const int f   = ksf - ksl * 3;
            const int bn  = f * 16 + (L & 15);         // B column 0..47
            const int bk  = (half * HALF_KS + ksl) * 32 + (L >> 4) * 8;
            bf16x8 w;
#pragma unroll
            for (int j = 0; j < 8; ++j) w[j] = (__bf16)0.0f;
            if (bn < 35) {
                const float* src = (bn < 5) ? (W_status + bn * 1024 + bk)
                                            : (W_flight + (bn - 5) * 1024 + bk);
                const float4 w0 = *(const float4*)(src);
                const float4 w1 = *(const float4*)(src + 4);
                w[0] = (__bf16)w0.x; w[1] = (__bf16)w0.y;
                w[2] = (__bf16)w0.z; w[3] = (__bf16)w0.w;
                w[4] = (__bf16)w1.x; w[5] = (__bf16)w1.y;
                w[6] = (__bf16)w1.z; w[7] = (__bf16)w1.w;
            }
            Bsh[d] = w;
        }
    };

    f32x4 acc0 = {0.f, 0.f, 0.f, 0.f};
    f32x4 acc1 = {0.f, 0.f, 0.f, 0.f};
    f32x4 acc2 = {0.f, 0.f, 0.f, 0.f};

    // ---- prologue: tile0 -> buf0, tile1 -> regs, B half0 ----
    float4 sr0 = E4[(size_t)(row0 + srow)       * 256 + 0 * 8 + sc4];
    float4 sr1 = E4[(size_t)(row0 + srow + 128) * 256 + 0 * 8 + sc4];
    Atile[0][srow * 8 + sswz]         = sr0;
    Atile[0][(srow + 128) * 8 + sswz] = sr1;
    sr0 = E4[(size_t)(row0 + srow)       * 256 + 1 * 8 + sc4];
    sr1 = E4[(size_t)(row0 + srow + 128) * 256 + 1 * 8 + sc4];
    stageB(0);
    __syncthreads();

    for (int half = 0; half < 2; ++half) {
        if (half == 1) {
            stageB(1);          // previous iter's barrier ordered all Bsh reads
            __syncthreads();
        }
#pragma unroll
        for (int kl = 0; kl < HALF_KS; ++kl) {
            const int ks   = half * HALF_KS + kl;
            const int buf  = kl & 1;        // == ks & 1 (HALF_KS even)
            const int nbuf = buf ^ 1;

            // ---- compute tile ks from LDS ----
            const float4 a0 = Atile[buf][abase + ((q * 2)     ^ aswz)];
            const float4 a1 = Atile[buf][abase + ((q * 2 + 1) ^ aswz)];
            bf16x8 af;
            af[0] = (__bf16)a0.x; af[1] = (__bf16)a0.y;
            af[2] = (__bf16)a0.z; af[3] = (__bf16)a0.w;
            af[4] = (__bf16)a1.x; af[5] = (__bf16)a1.y;
            af[6] = (__bf16)a1.z; af[7] = (__bf16)a1.w;

            const bf16x8 b0 = Bsh[(kl * 3 + 0) * 64 + lane];
            const bf16x8 b1 = Bsh[(kl * 3 + 1) * 64 + lane];
            const bf16x8 b2 = Bsh[(kl * 3 + 2) * 64 + lane];

            acc0 = __builtin_amdgcn_mfma_f32_16x16x32_bf16(af, b0, acc0, 0, 0, 0);
            acc1 = __builtin_amdgcn_mfma_f32_16x16x32_bf16(af, b1, acc1, 0, 0, 0);
            acc2 = __builtin_amdgcn_mfma_f32_16x16x32_bf16(af, b2, acc2, 0, 0, 0);

            // ---- store tile ks+1 (regs, loaded an iteration ago) ----
            Atile[nbuf][srow * 8 + sswz]         = sr0;
            Atile[nbuf][(srow + 128) * 8 + sswz] = sr1;

            // ---- issue loads for tile ks+2 (clamped; redundant tail hits L1) ----
            const int nt = (ks + 2 < KSTEPS) ? ks + 2 : KSTEPS - 1;
            sr0 = E4[(size_t)(row0 + srow)       * 256 + nt * 8 + sc4];
            sr1 = E4[(size_t)(row0 + srow + 128) * 256 + nt * 8 + sc4];

            __syncthreads();   // tile ks+1 visible; tile ks safe to overwrite
        }
    }

    // ---- epilogue: per-row dual softmax across the 16-lane group ----
    // lane holds cols n, 16+n, 32+n for rows q*4+i (C/D: col=lane&15,
    // row=(lane>>4)*4+reg).
    const float bias0 = (n < 5) ? b_status[n] : b_flight[n - 5];
    const float bias1 = b_flight[n + 11];
    const float bias2 = (n < 3) ? b_flight[n + 27] : 0.0f;
    const int   gb    = lane & 48;   // group base lane

    const int rowbase = row0 + wv * 16;
#pragma unroll
    for (int i = 0; i < 4; ++i) {
        const float v0 = acc0[i] + bias0;                         // col n
        const float v1 = acc1[i] + bias1;                         // col 16+n
        const float v2 = (n < 3) ? (acc2[i] + bias2) : -INFINITY; // col 32+n

        float ms = (n < 5) ? v0 : -INFINITY;                      // status max
        float mf = fmaxf((n >= 5) ? v0 : -INFINITY, fmaxf(v1, v2)); // flight max
#pragma unroll
        for (int m = 1; m < 16; m <<= 1) {
            ms = fmaxf(ms, __shfl_xor(ms, m));
            mf = fmaxf(mf, __shfl_xor(mf, m));
        }

        const float es  = (n < 5)  ? __expf(v0 - ms) : 0.0f;
        const float ef0 = (n >= 5) ? __expf(v0 - mf) : 0.0f;
        const float ef1 = __expf(v1 - mf);
        const float ef2 = (n < 3)  ? __expf(v2 - mf) : 0.0f;

        float ss = es;
        float sf = ef0 + ef1 + ef2;
#pragma unroll
        for (int m = 1; m < 16; m <<= 1) {
            ss += __shfl_xor(ss, m);
            sf += __shfl_xor(sf, m);
        }
        const float invs = 1.0f / ss;
        const float invf = 1.0f / sf;

        const float book   = __shfl(es, gb + 4) * invs * invf;    // s4
        const float change = __shfl(es, gb + 3) * invs * invf;    // s3

        float* orow = out + (size_t)(rowbase + q * 4 + i) * 63;
        if (n == 0) orow[0] = es * invs;            // no_flight  (status 0)
        if (n == 2) orow[1] = es * invs;            // cancel     (status 2)
        if (n == 1) orow[2] = es * invs;            // no_reservation (status 1)
        if (n >= 5) {                               // flight j = n-5
            orow[3 + (n - 5)]  = book   * ef0;
            orow[33 + (n - 5)] = change * ef0;
        }
        orow[3 + (n + 11)]  = book   * ef1;         // flight j = n+11
        orow[33 + (n + 11)] = change * ef1;
        if (n < 3) {                                // flight j = n+27
            orow[3 + (n + 27)]  = book   * ef2;
            orow[33 + (n + 27)] = change * ef2;
        }
    }
}

extern "C" void kernel_launch(void* const* d_in, const int* in_sizes, int n_in,
                              void* d_out, int out_size, void* d_ws, size_t ws_size,
                              hipStream_t stream) {
    const float* embs     = (const float*)d_in[0];
    const float* W_status = (const float*)d_in[1];
    const float* b_status = (const float*)d_in[2];
    const float* W_flight = (const float*)d_in[3];
    const float* b_flight = (const float*)d_in[4];
    float* out = (float*)d_out;

    const int rows = in_sizes[0] / 1024;              // 65536
    const int grid = rows / 256;                      // 256

    fused_heads_kernel<<<grid, 1024, 0, stream>>>(
        embs, W_status, b_status, W_flight, b_flight, out);
}